// Round 10
// baseline (401.701 us; speedup 1.0000x reference)
//
#include <hip/hip_runtime.h>
#include <hip/hip_bf16.h>

typedef unsigned short u16;
typedef unsigned int u32;
typedef unsigned long long u64;
typedef __attribute__((ext_vector_type(8))) short short8;
typedef __attribute__((ext_vector_type(4))) float f32x4;

#define DI __device__ __forceinline__

DI float b2f(u16 v){ u32 u = ((u32)v) << 16; float f; __builtin_memcpy(&f, &u, 4); return f; }
DI u16 f2bu(float f){ __hip_bfloat16 h = __float2bfloat16(f); u16 u; __builtin_memcpy(&u, &h, 2); return u; }

// async 16B global->LDS DMA; LDS dest = wave-uniform base + lane*16
DI void gll16(const u16* g, u16* l){
  __builtin_amdgcn_global_load_lds((const __attribute__((address_space(1))) void*)g,
                                   (__attribute__((address_space(3))) void*)l, 16, 0, 0);
}

// ---------- kaux: fused kzero + kwt + kwr(wrb,w3b,w4b,e0,e1) + khpad ----------
__global__ __launch_bounds__(256) void kaux(const float* __restrict__ wt, const float* __restrict__ wrw,
      const float* __restrict__ g2, const float* __restrict__ v2,
      const float* __restrict__ gr, const float* __restrict__ vr,
      const float* __restrict__ w3, const float* __restrict__ w4,
      const float* __restrict__ bt, const float* __restrict__ bb2, const float* __restrict__ m2,
      const float* __restrict__ bbr, const float* __restrict__ mr, const float* __restrict__ brb,
      float* __restrict__ xm, u16* __restrict__ wtb, u16* __restrict__ wrb,
      u16* __restrict__ w3b, u16* __restrict__ w4b,
      float* __restrict__ e0, float* __restrict__ e1, u16* __restrict__ h){
  const int b = blockIdx.x, tid = threadIdx.x;
  if (b < 50){                       // xm = 0
    const int i = b*1024 + tid*4;
    float4 z = {0.f,0.f,0.f,0.f};
    *(float4*)(xm + i) = z;
  } else if (b < 626){               // wtb[dt][co][ci] = bf16(wt[co][ci][dt])
    const int o = (b-50)*256 + tid;
    const int dt = o >> 14, rem = o & 16383;
    wtb[o] = f2bu(wt[rem*9 + dt]);
  } else if (b < 658){               // wrb = wr * R0/E0
    const int o = (b-626)*256 + tid;
    const int co = o >> 6;
    const float E0 = g2[co]*rsqrtf(v2[co]+1e-5f);
    const float R0 = gr[co]*rsqrtf(vr[co]+1e-5f);
    wrb[o] = f2bu(wrw[o]*R0/E0);
  } else if (b < 690){               // w3b
    const int o = (b-658)*256 + tid;
    w3b[o] = f2bu(w3[o]);
  } else if (b < 722){               // w4b
    const int o = (b-690)*256 + tid;
    w4b[o] = f2bu(w4[o]);
  } else if (b < 786){               // h padding rows
    const int j = b - 722, n = j >> 1, side = j & 1;
    short8* base = (short8*)(h + ((size_t)n*6600 + (side ? 6500 : 0))*128);
    short8 z = {0,0,0,0,0,0,0,0};
    for (int i = tid; i < 1600; i += 256) base[i] = z;
  } else {                            // e0/e1 epilogue constants
    if (tid < 128){
      const float scv2 = g2[tid]*rsqrtf(v2[tid]+1e-5f);
      const float scvr = gr[tid]*rsqrtf(vr[tid]+1e-5f);
      e0[tid] = scv2;
      e1[tid] = scv2*bt[tid] + bb2[tid] - m2[tid]*scv2
              + (bbr[tid] - mr[tid]*scvr + scvr*brb[tid]);
    }
  }
}

// ---------- kprep2: fused kprep + kxa (t-aligned 200-col blocks); float4 x-loads ----------
__global__ __launch_bounds__(256) void kprep2(const float* __restrict__ x, const float* __restrict__ Ab,
                                              u16* __restrict__ xT, u16* __restrict__ xA){
  __shared__ float xl[200*68];
  __shared__ float al[625];
  const int tc = blockIdx.x, n = blockIdx.y, tid = threadIdx.x;
  const int x0t = tc * 200;
  for (int i = tid; i < 625; i += 256) al[i] = Ab[i];
  // load x tile fp32: 64 ci rows x 200 cols, float4 (16B/lane) coalesced
  for (int idx = tid; idx < 3200; idx += 256){
    const int ci = idx / 50, c4 = idx - ci*50;
    const float4 f = *(const float4*)(x + ((size_t)(n*64+ci))*6400 + x0t + c4*4);
    float* d = xl + (c4*4)*68 + ci;
    d[0] = f.x; d[68] = f.y; d[136] = f.z; d[204] = f.w;
  }
  __syncthreads();
  // xT store: bf16 pack, u64 (4 u16) per iter, coalesced
  for (int idx = tid; idx < 3200; idx += 256){
    const int r = idx >> 4, k4 = (idx & 15) << 2;
    const float* src = xl + r*68 + k4;
    u64 pk = (u64)f2bu(src[0]) | ((u64)f2bu(src[1])<<16)
           | ((u64)f2bu(src[2])<<32) | ((u64)f2bu(src[3])<<48);
    *(u64*)(xT + ((size_t)n*6400 + x0t + r)*64 + k4) = pk;
  }
  // A-mix (former kxa compute, verbatim)
  if (tid < 200){
    const int t_ = tid / 25, u = tid % 25;
    float acc[64];
    #pragma unroll
    for (int k = 0; k < 64; k++) acc[k] = 0.f;
    const float* arow = al + u*25;
    for (int v = 0; v < 25; v++){
      const float a = arow[v];
      const float* xr = xl + (t_*25 + v)*68;
      #pragma unroll
      for (int k = 0; k < 64; k++) acc[k] += a * xr[k];
    }
    u16* dst = xA + ((size_t)n*6400 + x0t + tid)*64;
    #pragma unroll
    for (int k = 0; k < 64; k += 4){
      u64 pk = (u64)f2bu(acc[k]) | ((u64)f2bu(acc[k+1])<<16)
             | ((u64)f2bu(acc[k+2])<<32) | ((u64)f2bu(acc[k+3])<<48);
      *(u64*)(dst + k) = pk;
    }
  }
}

// ---------- kmean ----------
__global__ __launch_bounds__(256) void kmean(const u16* __restrict__ xT, float* __restrict__ xm){
  __shared__ float part[4][1600];
  const int seg = blockIdx.x, n = blockIdx.y, tid = threadIdx.x;
  const int tg = tid>>6, c = tid&63;
  float acc[25];
  #pragma unroll
  for (int v=0;v<25;v++) acc[v]=0.f;
  for (int t = seg*32 + tg; t < seg*32 + 32; t += 4){
    const u16* base = xT + ((size_t)n*6400 + t*25)*64 + c;
    #pragma unroll
    for (int v=0;v<25;v++) acc[v] += b2f(base[v*64]);
  }
  #pragma unroll
  for (int v=0;v<25;v++) part[tg][v*64+c] = acc[v];
  __syncthreads();
  for (int idx = tid; idx < 1600; idx += 256){
    const int v = idx>>6, cc = idx&63;
    const float m = part[0][idx]+part[1][idx]+part[2][idx]+part[3][idx];
    atomicAdd(&xm[(n*64+cc)*25+v], m*(1.f/256.f));
  }
}

// ---------- kp ----------
__global__ __launch_bounds__(64) void kp(const float* __restrict__ xm, const float* __restrict__ w2,
                                         const float* __restrict__ b2p, const float* __restrict__ Ab,
                                         float* __restrict__ p, float* __restrict__ rsA){
  const int c = blockIdx.x, n = blockIdx.y, lane = threadIdx.x;
  __shared__ float sc[32];
  __shared__ float red[2];
  float neg = 0.f;
  if (lane < 25){
    float acc = b2p[c];
    for (int k = 0; k < 64; k++) acc += w2[c*64 + k] * xm[(n*64 + k)*25 + lane];
    neg = -acc;
    sc[lane] = neg;
  }
  __syncthreads();
  if (lane == 0){
    float m = sc[0];
    for (int i = 1; i < 25; i++) m = fmaxf(m, sc[i]);
    red[0] = m;
  }
  __syncthreads();
  float e = 0.f;
  if (lane < 25){ e = expf(neg - red[0]); sc[lane] = e; }
  __syncthreads();
  if (lane == 0){
    float ssum = 0.f;
    for (int i = 0; i < 25; i++) ssum += sc[i];
    red[1] = ssum;
  }
  __syncthreads();
  if (lane < 25) p[(n*32 + c)*25 + lane] = e / red[1];
  if (n == 0 && c == 0 && lane < 25){
    float r = 0.f;
    for (int v = 0; v < 25; v++) r += Ab[lane*25 + v];
    rsA[lane] = r;
  }
}

// ---------- ks (atomic-free; w3 staged as pre-converted bf16) ----------
__global__ __launch_bounds__(256) void ks(const u16* __restrict__ xT, const u16* __restrict__ w3b,
                                          const float* __restrict__ p, float* __restrict__ s){
  __shared__ __align__(16) char smem[53248];
  __shared__ float pL[800];
  u16* aL = (u16*)smem;
  u16* bL = (u16*)(smem + 18432);
  float* z3 = (float*)smem;
  const int xb = blockIdx.x, n = blockIdx.y, tid = threadIdx.x;
  const int x0 = xb*100, t0 = xb*4;
  const int row = tid >> 1, half = tid & 1;
  {
    short8* dst = (short8*)(aL + row*72 + half*32);
    const short8* src = (const short8*)(w3b + row*64 + half*32);
    #pragma unroll
    for (int i=0;i<4;i++) dst[i] = src[i];
  }
  {
    short8* dst = (short8*)(bL + row*72 + half*32);
    if (row < 100){
      const short8* src = (const short8*)(xT + ((size_t)n*6400 + x0 + row)*64 + half*32);
      #pragma unroll
      for (int i=0;i<4;i++) dst[i] = src[i];
    } else {
      short8 z = {0,0,0,0,0,0,0,0};
      #pragma unroll
      for (int i=0;i<4;i++) dst[i] = z;
    }
  }
  for (int i = tid; i < 800; i += 256) pL[i] = p[n*800 + i];
  __syncthreads();
  const int wave = tid>>6, lane = tid&63, q = lane>>4, l = lane&15;
  const int wr = wave>>1, wc = wave&1;
  f32x4 acc[4][4];
  #pragma unroll
  for (int i=0;i<4;i++)
    #pragma unroll
    for (int j=0;j<4;j++){ f32x4 z0 = {0.f,0.f,0.f,0.f}; acc[i][j] = z0; }
  #pragma unroll
  for (int ksi = 0; ksi < 2; ksi++){
    const int kb = ksi*32 + q*8;
    short8 af[4], bf[4];
    #pragma unroll
    for (int i=0;i<4;i++) af[i] = *(const short8*)(aL + (wr*64 + i*16 + l)*72 + kb);
    #pragma unroll
    for (int j=0;j<4;j++) bf[j] = *(const short8*)(bL + (wc*64 + j*16 + l)*72 + kb);
    #pragma unroll
    for (int i=0;i<4;i++)
      #pragma unroll
      for (int j=0;j<4;j++)
        acc[i][j] = __builtin_amdgcn_mfma_f32_16x16x32_bf16(af[i], bf[j], acc[i][j], 0, 0, 0);
  }
  __syncthreads();
  #pragma unroll
  for (int i=0;i<4;i++){
    const int co0 = wr*64 + i*16 + q*4;
    #pragma unroll
    for (int j=0;j<4;j++){
      const int colx = wc*64 + j*16 + l;
      if (colx < 100){
        #pragma unroll
        for (int r=0;r<4;r++) z3[(co0 + r)*104 + colx] = acc[i][j][r];
      }
    }
  }
  __syncthreads();
  for (int idx = tid; idx < 512; idx += 256){
    const int co = idx >> 2, tt = idx & 3;
    const float* zr = z3 + co*104 + tt*25;
    const float* pr = pL + (co & 31)*25;
    float acc2 = 0.f;
    #pragma unroll
    for (int v=0; v<25; v++) acc2 += zr[v]*pr[v];
    s[((size_t)n*128 + co)*256 + t0 + tt] = acc2;
  }
}

// ---------- ky (w4 staged as pre-converted bf16) ----------
__global__ __launch_bounds__(256) void ky(const u16* __restrict__ xA, const u16* __restrict__ w4b,
      const float* __restrict__ s, const float* __restrict__ b3, const float* __restrict__ b4,
      const float* __restrict__ g1, const float* __restrict__ bb1, const float* __restrict__ m1,
      const float* __restrict__ v1, const float* __restrict__ rsA, u16* __restrict__ h){
  __shared__ __align__(16) u16 aL[128*72];
  __shared__ __align__(16) u16 bL[128*72];
  __shared__ float A0[128], A1[128], A2[128];
  __shared__ float sF[1024];
  __shared__ float rs[32];
  const int xb = blockIdx.x, n = blockIdx.y, tid = threadIdx.x;
  const int x0 = xb*128, tlo = x0/25;
  const int row = tid >> 1, half = tid & 1;
  {
    short8* dst = (short8*)(aL + row*72 + half*32);
    const short8* src = (const short8*)(w4b + row*64 + half*32);
    #pragma unroll
    for (int i=0;i<4;i++) dst[i] = src[i];
  }
  {
    const short8* src = (const short8*)(xA + ((size_t)n*6400 + x0 + row)*64 + half*32);
    short8* dst = (short8*)(bL + row*72 + half*32);
    #pragma unroll
    for (int i=0;i<4;i++) dst[i] = src[i];
  }
  if (tid < 128){
    const float scv = g1[tid] * rsqrtf(v1[tid] + 1e-5f);
    A0[tid] = scv;
    A1[tid] = scv * b4[tid];
    A2[tid] = bb1[tid] - m1[tid] * scv;
  }
  if (tid < 32) rs[tid] = (tid < 25) ? rsA[tid] : 0.f;
  __syncthreads();
  for (int idx = tid; idx < 1024; idx += 256){
    const int co = idx >> 3, tt = idx & 7;
    const int t = tlo + tt;
    const float sv = (t < 256) ? s[((size_t)n*128 + co)*256 + t] : 0.f;
    sF[idx] = A0[co] * (sv + b3[co]) + A2[co];
  }
  const int wave = tid>>6, lane = tid&63, q = lane>>4, l = lane&15;
  const int wr = wave>>1, wc = wave&1;
  f32x4 acc[4][4];
  #pragma unroll
  for (int i=0;i<4;i++)
    #pragma unroll
    for (int j=0;j<4;j++){ f32x4 z0 = {0.f,0.f,0.f,0.f}; acc[i][j] = z0; }
  #pragma unroll
  for (int ksi = 0; ksi < 2; ksi++){
    const int kb = ksi*32 + q*8;
    short8 af[4], bf[4];
    #pragma unroll
    for (int i=0;i<4;i++) af[i] = *(const short8*)(aL + (wr*64 + i*16 + l)*72 + kb);
    #pragma unroll
    for (int j=0;j<4;j++) bf[j] = *(const short8*)(bL + (wc*64 + j*16 + l)*72 + kb);
    #pragma unroll
    for (int i=0;i<4;i++)
      #pragma unroll
      for (int j=0;j<4;j++)
        acc[i][j] = __builtin_amdgcn_mfma_f32_16x16x32_bf16(af[i], bf[j], acc[i][j], 0, 0, 0);
  }
  __syncthreads();
  #pragma unroll
  for (int i=0;i<4;i++){
    const int co0 = wr*64 + i*16 + q*4;
    #pragma unroll
    for (int j=0;j<4;j++){
      const int colx = wc*64 + j*16 + l;
      const int xg = x0 + colx;
      const int u = xg % 25, tt = xg/25 - tlo;
      const float rsu = rs[u];
      u64 pk = 0;
      #pragma unroll
      for (int r=0;r<4;r++){
        const int co = co0 + r;
        float y = A0[co]*acc[i][j][r] + A1[co]*rsu + sF[co*8 + tt];
        y = fmaxf(y, 0.f);
        pk |= ((u64)f2bu(y)) << (16*r);
      }
      *(u64*)(h + ((size_t)n*6600 + xg + 100)*128 + co0) = pk;
    }
  }
}

// ---------- ktcn v8: v7 schedule + K-split 64x64 wave tiles ----------
// R9 arithmetic: v7's three resources (LDS ~37-60us, HBM ~30, MFMA ~26) are near-
// serialized; LDS operand traffic dominates and scales with wave-tile perimeter.
// v8: 2x2 grid of 64x64 positions, 2 waves/position split K (kh=0: k0..63,
// kh=1: k64..127). Per-lane LDS bytes/tap 384->256 (-33%) at same MFMA count.
// One end-of-kernel LDS reduction (64KB, reuses dead hW region) sums K-halves.
// Staging + counted-vmcnt ledger is tid-indexed — byte-identical to v7 (verified).
__global__ __launch_bounds__(512, 2) void ktcn(const u16* __restrict__ h, const u16* __restrict__ wtb,
      const u16* __restrict__ wrb, const u16* __restrict__ xT,
      const float* __restrict__ e0g, const float* __restrict__ e1g,
      float* __restrict__ out){
  // LDS: [0,83968) hW 328 rows x 128 u16 (chunk-swizzled); [83968,116736) Abuf0; [116736,149504) Abuf1
  // after taps: [0,65536) reused as fp32 K-half reduction buffer
  __shared__ __align__(16) char smem[149504];
  u16* hW = (u16*)smem;
  u16* Ab0 = (u16*)(smem + 83968);
  u16* Ab1 = (u16*)(smem + 116736);
  float* red = (float*)smem;
  const int xb = blockIdx.x, n = blockIdx.y, tid = threadIdx.x;
  const int x0 = xb*128;
  const int wave = tid>>6, lane = tid&63, q = lane>>4, l = lane&15;
  const int wr2 = (wave>>2)&1, wc2 = (wave>>1)&1, kh = wave&1; // 2x2 pos, K-half
  const u16* hbase = h + ((size_t)n*6600 + x0)*128;
  const u16* xtb = xT + ((size_t)n*6400 + x0)*64;

  // epilogue scale/shift into regs (oldest in FIFO, drained at B_pre)
  f32x4 e0r[4], e1r[4];
  #pragma unroll
  for (int i=0;i<4;i++){
    const int co0 = wr2*64 + i*16 + q*4;
    e0r[i] = *(const f32x4*)(e0g + co0);
    e1r[i] = *(const f32x4*)(e1g + co0);
  }

  // p1: hW rows 0..127 (its 0..3)
  #pragma unroll
  for (int it = 0; it < 4; ++it){
    const int ci = it*512 + tid;
    const int r = ci >> 4, c = ci & 15;
    gll16(hbase + r*128 + ((c ^ (r & 15))<<3), hW + ((it*512 + wave*64)<<3));
  }
  // A0 (tap 0 weights)
  #pragma unroll
  for (int it = 0; it < 4; ++it){
    const int ci = it*512 + tid;
    const int r = ci >> 4, c = ci & 15;
    gll16(wtb + r*128 + ((c ^ (r & 15))<<3), Ab0 + ((it*512 + wave*64)<<3));
  }
  // A1 (tap 1 weights)
  #pragma unroll
  for (int it = 0; it < 4; ++it){
    const int ci = it*512 + tid;
    const int r = ci >> 4, c = ci & 15;
    gll16(wtb + 16384 + r*128 + ((c ^ (r & 15))<<3), Ab1 + ((it*512 + wave*64)<<3));
  }
  // it4, it5: hW rows 128..191 (covers taps 1,2 needs)
  #pragma unroll
  for (int it = 4; it < 6; ++it){
    const int ci = it*512 + tid;
    const int r = ci >> 4, c = ci & 15;
    gll16(hbase + r*128 + ((c ^ (r & 15))<<3), hW + ((it*512 + wave*64)<<3));
  }

  f32x4 acc[4][4];
  #pragma unroll
  for (int i=0;i<4;i++)
    #pragma unroll
    for (int j=0;j<4;j++){ f32x4 z0 = {0.f,0.f,0.f,0.f}; acc[i][j] = z0; }

  // B_pre: require E + p1 + A0 complete; allow A1 + it4 + it5 (6 newest ops/thread) in flight
  asm volatile("s_waitcnt vmcnt(6) lgkmcnt(0)" ::: "memory");
  __builtin_amdgcn_s_barrier();
  __builtin_amdgcn_sched_barrier(0);

  #pragma unroll 1
  for (int dt = 0; dt <= 9; ++dt){
    // A-prefetch: taps 1..7 issue A(dt+1) into the buffer not being read this tap
    if (dt >= 1 && dt <= 7){
      const u16* gA = wtb + (dt+1)*16384;
      u16* dA = ((dt+1) & 1) ? Ab1 : Ab0;
      #pragma unroll
      for (int it = 0; it < 4; ++it){
        const int ci = it*512 + tid;
        const int r = ci >> 4, c = ci & 15;
        gll16(gA + r*128 + ((c ^ (r & 15))<<3), dA + ((it*512 + wave*64)<<3));
      }
    } else if (dt == 8){
      // residual operands into Ab1: wrb (16 KB) then xT tile (16 KB)
      #pragma unroll
      for (int it = 0; it < 2; ++it){
        const int ci = it*512 + tid;
        const int r = ci >> 3, c = ci & 7;
        gll16(wrb + r*64 + ((c ^ (r & 7))<<3), Ab1 + ((it*512 + wave*64)<<3));
      }
      #pragma unroll
      for (int it = 0; it < 2; ++it){
        const int ci = it*512 + tid;
        const int r = ci >> 3, c = ci & 7;
        gll16(xtb + r*64 + ((c ^ (r & 7))<<3), Ab1 + 8192 + ((it*512 + wave*64)<<3));
      }
    }
    // streamed hW remainder: taps 1..4 issue it6..it9 (+tail at dt=4)
    if (dt >= 1 && dt <= 4){
      const int it = 5 + dt;   // 6..9, rows 192..319
      const int ci = it*512 + tid;
      const int r = ci >> 4, c = ci & 15;
      gll16(hbase + r*128 + ((c ^ (r & 15))<<3), hW + ((it*512 + wave*64)<<3));
      if (dt == 4 && tid < 128){  // tail rows 320..327 (waves 0,1)
        const int ci2 = 5120 + tid;
        const int r2 = ci2 >> 4, c2 = ci2 & 15;
        gll16(hbase + r2*128 + ((c2 ^ (r2 & 15))<<3), hW + ((5120 + wave*64)<<3));
      }
    }
    // compute: this wave's K-half (kh) of its 64x64 position (wr2,wc2)
    if (dt < 9){
      const u16* A = (dt & 1) ? Ab1 : Ab0;
      #pragma unroll
      for (int ks2 = 0; ks2 < 2; ks2++){
        const int c0 = (kh*2 + ks2)*4 + q;
        short8 af[4], bf[4];
        #pragma unroll
        for (int i=0;i<4;i++){
          const int r = wr2*64 + i*16 + l;
          af[i] = *(const short8*)(A + (((r<<4) + (c0 ^ (r & 15)))<<3));
        }
        #pragma unroll
        for (int j=0;j<4;j++){
          const int r = dt*25 + wc2*64 + j*16 + l;
          bf[j] = *(const short8*)(hW + (((r<<4) + (c0 ^ (r & 15)))<<3));
        }
        #pragma unroll
        for (int i=0;i<4;i++)
          #pragma unroll
          for (int j=0;j<4;j++)
            acc[i][j] = __builtin_amdgcn_mfma_f32_16x16x32_bf16(af[i], bf[j], acc[i][j], 0, 0, 0);
      }
    } else {
      // residual tap: K=64 split across kh (kh=0: k0..31, kh=1: k32..63)
      const u16* A = Ab1;
      const u16* B = Ab1 + 8192;
      const int c0 = kh*4 + q;
      short8 af[4], bf[4];
      #pragma unroll
      for (int i=0;i<4;i++){
        const int r = wr2*64 + i*16 + l;
        af[i] = *(const short8*)(A + (((r<<3) + (c0 ^ (r & 7)))<<3));
      }
      #pragma unroll
      for (int j=0;j<4;j++){
        const int r = wc2*64 + j*16 + l;
        bf[j] = *(const short8*)(B + (((r<<3) + (c0 ^ (r & 7)))<<3));
      }
      #pragma unroll
      for (int i=0;i<4;i++)
        #pragma unroll
        for (int j=0;j<4;j++)
          acc[i][j] = __builtin_amdgcn_mfma_f32_16x16x32_bf16(af[i], bf[j], acc[i][j], 0, 0, 0);
    }
    // barrier: counted for dt<=4; plain syncthreads from dt=5
    if (dt < 9){
      if (dt <= 4){
        asm volatile("s_waitcnt vmcnt(1) lgkmcnt(0)" ::: "memory");
        __builtin_amdgcn_s_barrier();
        __builtin_amdgcn_sched_barrier(0);
      } else {
        __syncthreads();
      }
    }
  }

  // ---- K-half reduction: kh=1 writes partials to LDS (dead hW region), kh=0 adds ----
  const int pos = wr2*2 + wc2;
  float* rb = red + pos*4096;
  if (kh == 1){
    #pragma unroll
    for (int i=0;i<4;i++)
      #pragma unroll
      for (int j=0;j<4;j++)
        #pragma unroll
        for (int r=0;r<4;r++)
          rb[(i*16 + q*4 + r)*64 + j*16 + l] = acc[i][j][r];
  }
  __syncthreads();
  if (kh == 0){
    #pragma unroll
    for (int i=0;i<4;i++){
      const int co0 = wr2*64 + i*16 + q*4;
      #pragma unroll
      for (int j=0;j<4;j++){
        const int colx = wc2*64 + j*16 + l;
        #pragma unroll
        for (int r=0;r<4;r++){
          const float v = acc[i][j][r] + rb[(i*16 + q*4 + r)*64 + j*16 + l];
          const float yv = e0r[i][r]*v + e1r[i][r];
          out[((size_t)n*128 + co0 + r)*6400 + x0 + colx] = fmaxf(yv, 0.f);
        }
      }
    }
  }
}

extern "C" void kernel_launch(void* const* d_in, const int* in_sizes, int n_in,
                              void* d_out, int out_size, void* d_ws, size_t ws_size,
                              hipStream_t stream){
  const float* x   = (const float*)d_in[0];
  const float* Ab  = (const float*)d_in[1];
  // d_in[2],d_in[3] = w1,b1: dead (softmax cancellation)
  const float* w2  = (const float*)d_in[4];
  const float* b2p = (const float*)d_in[5];
  const float* w3  = (const float*)d_in[6];
  const float* b3  = (const float*)d_in[7];
  const float* w4  = (const float*)d_in[8];
  const float* b4  = (const float*)d_in[9];
  const float* g1  = (const float*)d_in[10];
  const float* bb1 = (const float*)d_in[11];
  const float* m1  = (const float*)d_in[12];
  const float* v1  = (const float*)d_in[13];
  const float* wt  = (const float*)d_in[14];
  const float* bt  = (const float*)d_in[15];
  const float* g2  = (const float*)d_in[16];
  const float* bb2 = (const float*)d_in[17];
  const float* m2  = (const float*)d_in[18];
  const float* v2  = (const float*)d_in[19];
  const float* wrw = (const float*)d_in[20];
  const float* brb = (const float*)d_in[21];
  const float* gr  = (const float*)d_in[22];
  const float* bbr = (const float*)d_in[23];
  const float* mr  = (const float*)d_in[24];
  const float* vr  = (const float*)d_in[25];
  float* out = (float*)d_out;

  char* ws = (char*)d_ws;
  float* xm  = (float*)(ws);               // 204,800 B
  float* p   = (float*)(ws + 204800);      // 102,400 B
  float* rsA = (float*)(ws + 307200);      // 512 B
  float* s   = (float*)(ws + 307712);      // 4,194,304 B
  u16* xT    = (u16*)(ws + 4502016);       // 26,214,400 B  [n][6400][64]
  u16* xA    = (u16*)(ws + 30716416);      // 26,214,400 B  [n][6400][64]
  u16* h     = (u16*)(ws + 56930816);      // 54,067,200 B  [n][6600][128]
  u16* wtb   = (u16*)(ws + 110998016);     // 294,912 B     [9][128][128]
  u16* wrb   = (u16*)(ws + 111292928);     // 16,384 B      [128][64]
  u16* w3b   = (u16*)(ws + 111309312);     // 16,384 B      [128][64]
  u16* w4b   = (u16*)(ws + 111325696);     // 16,384 B      [128][64]
  float* e0  = (float*)(ws + 111342080);   // 512 B
  float* e1  = (float*)(ws + 111342592);   // 512 B

  kaux<<<787, 256, 0, stream>>>(wt, wrw, g2, v2, gr, vr, w3, w4, bt, bb2, m2, bbr, mr, brb,
                                xm, wtb, wrb, w3b, w4b, e0, e1, h);
  kprep2<<<dim3(32,32), 256, 0, stream>>>(x, Ab, xT, xA);
  kmean<<<dim3(8,32), 256, 0, stream>>>(xT, xm);
  kp<<<dim3(32,32), 64, 0, stream>>>(xm, w2, b2p, Ab, p, rsA);
  ks<<<dim3(64,32), 256, 0, stream>>>(xT, w3b, p, s);
  ky<<<dim3(50,32), 256, 0, stream>>>(xA, w4b, s, b3, b4, g1, bb1, m1, v1, rsA, h);
  ktcn<<<dim3(50,32), 512, 0, stream>>>(h, wtb, wrb, xT, e0, e1, out);
}

// Round 12
// 397.157 us; speedup vs baseline: 1.0114x; 1.0114x over previous
//
#include <hip/hip_runtime.h>
#include <hip/hip_bf16.h>

typedef unsigned short u16;
typedef unsigned int u32;
typedef unsigned long long u64;
typedef __attribute__((ext_vector_type(8))) short short8;
typedef __attribute__((ext_vector_type(4))) float f32x4;

#define DI __device__ __forceinline__

DI float b2f(u16 v){ u32 u = ((u32)v) << 16; float f; __builtin_memcpy(&f, &u, 4); return f; }
DI u16 f2bu(float f){ __hip_bfloat16 h = __float2bfloat16(f); u16 u; __builtin_memcpy(&u, &h, 2); return u; }

// async 16B global->LDS DMA; LDS dest = wave-uniform base + lane*16
DI void gll16(const u16* g, u16* l){
  __builtin_amdgcn_global_load_lds((const __attribute__((address_space(1))) void*)g,
                                   (__attribute__((address_space(3))) void*)l, 16, 0, 0);
}

// ---------- kaux: fused kzero + kwt + kwr(wrb,w3b,w4b,e0,e1) + khpad ----------
__global__ __launch_bounds__(256) void kaux(const float* __restrict__ wt, const float* __restrict__ wrw,
      const float* __restrict__ g2, const float* __restrict__ v2,
      const float* __restrict__ gr, const float* __restrict__ vr,
      const float* __restrict__ w3, const float* __restrict__ w4,
      const float* __restrict__ bt, const float* __restrict__ bb2, const float* __restrict__ m2,
      const float* __restrict__ bbr, const float* __restrict__ mr, const float* __restrict__ brb,
      float* __restrict__ xm, u16* __restrict__ wtb, u16* __restrict__ wrb,
      u16* __restrict__ w3b, u16* __restrict__ w4b,
      float* __restrict__ e0, float* __restrict__ e1, u16* __restrict__ h){
  const int b = blockIdx.x, tid = threadIdx.x;
  if (b < 50){                       // xm = 0
    const int i = b*1024 + tid*4;
    float4 z = {0.f,0.f,0.f,0.f};
    *(float4*)(xm + i) = z;
  } else if (b < 626){               // wtb[dt][co][ci] = bf16(wt[co][ci][dt])
    const int o = (b-50)*256 + tid;
    const int dt = o >> 14, rem = o & 16383;
    wtb[o] = f2bu(wt[rem*9 + dt]);
  } else if (b < 658){               // wrb = wr * R0/E0
    const int o = (b-626)*256 + tid;
    const int co = o >> 6;
    const float E0 = g2[co]*rsqrtf(v2[co]+1e-5f);
    const float R0 = gr[co]*rsqrtf(vr[co]+1e-5f);
    wrb[o] = f2bu(wrw[o]*R0/E0);
  } else if (b < 690){               // w3b
    const int o = (b-658)*256 + tid;
    w3b[o] = f2bu(w3[o]);
  } else if (b < 722){               // w4b
    const int o = (b-690)*256 + tid;
    w4b[o] = f2bu(w4[o]);
  } else if (b < 786){               // h padding rows
    const int j = b - 722, n = j >> 1, side = j & 1;
    short8* base = (short8*)(h + ((size_t)n*6600 + (side ? 6500 : 0))*128);
    short8 z = {0,0,0,0,0,0,0,0};
    for (int i = tid; i < 1600; i += 256) base[i] = z;
  } else {                            // e0/e1 epilogue constants
    if (tid < 128){
      const float scv2 = g2[tid]*rsqrtf(v2[tid]+1e-5f);
      const float scvr = gr[tid]*rsqrtf(vr[tid]+1e-5f);
      e0[tid] = scv2;
      e1[tid] = scv2*bt[tid] + bb2[tid] - m2[tid]*scv2
              + (bbr[tid] - mr[tid]*scvr + scvr*brb[tid]);
    }
  }
}

// ---------- kprep2: fused kprep + kxa (t-aligned 200-col blocks); float4 x-loads ----------
__global__ __launch_bounds__(256) void kprep2(const float* __restrict__ x, const float* __restrict__ Ab,
                                              u16* __restrict__ xT, u16* __restrict__ xA){
  __shared__ float xl[200*68];
  __shared__ float al[625];
  const int tc = blockIdx.x, n = blockIdx.y, tid = threadIdx.x;
  const int x0t = tc * 200;
  for (int i = tid; i < 625; i += 256) al[i] = Ab[i];
  // load x tile fp32: 64 ci rows x 200 cols, float4 (16B/lane) coalesced
  for (int idx = tid; idx < 3200; idx += 256){
    const int ci = idx / 50, c4 = idx - ci*50;
    const float4 f = *(const float4*)(x + ((size_t)(n*64+ci))*6400 + x0t + c4*4);
    float* d = xl + (c4*4)*68 + ci;
    d[0] = f.x; d[68] = f.y; d[136] = f.z; d[204] = f.w;
  }
  __syncthreads();
  // xT store: bf16 pack, u64 (4 u16) per iter, coalesced
  for (int idx = tid; idx < 3200; idx += 256){
    const int r = idx >> 4, k4 = (idx & 15) << 2;
    const float* src = xl + r*68 + k4;
    u64 pk = (u64)f2bu(src[0]) | ((u64)f2bu(src[1])<<16)
           | ((u64)f2bu(src[2])<<32) | ((u64)f2bu(src[3])<<48);
    *(u64*)(xT + ((size_t)n*6400 + x0t + r)*64 + k4) = pk;
  }
  // A-mix (former kxa compute, verbatim)
  if (tid < 200){
    const int t_ = tid / 25, u = tid % 25;
    float acc[64];
    #pragma unroll
    for (int k = 0; k < 64; k++) acc[k] = 0.f;
    const float* arow = al + u*25;
    for (int v = 0; v < 25; v++){
      const float a = arow[v];
      const float* xr = xl + (t_*25 + v)*68;
      #pragma unroll
      for (int k = 0; k < 64; k++) acc[k] += a * xr[k];
    }
    u16* dst = xA + ((size_t)n*6400 + x0t + tid)*64;
    #pragma unroll
    for (int k = 0; k < 64; k += 4){
      u64 pk = (u64)f2bu(acc[k]) | ((u64)f2bu(acc[k+1])<<16)
             | ((u64)f2bu(acc[k+2])<<32) | ((u64)f2bu(acc[k+3])<<48);
      *(u64*)(dst + k) = pk;
    }
  }
}

// ---------- kmean ----------
__global__ __launch_bounds__(256) void kmean(const u16* __restrict__ xT, float* __restrict__ xm){
  __shared__ float part[4][1600];
  const int seg = blockIdx.x, n = blockIdx.y, tid = threadIdx.x;
  const int tg = tid>>6, c = tid&63;
  float acc[25];
  #pragma unroll
  for (int v=0;v<25;v++) acc[v]=0.f;
  for (int t = seg*32 + tg; t < seg*32 + 32; t += 4){
    const u16* base = xT + ((size_t)n*6400 + t*25)*64 + c;
    #pragma unroll
    for (int v=0;v<25;v++) acc[v] += b2f(base[v*64]);
  }
  #pragma unroll
  for (int v=0;v<25;v++) part[tg][v*64+c] = acc[v];
  __syncthreads();
  for (int idx = tid; idx < 1600; idx += 256){
    const int v = idx>>6, cc = idx&63;
    const float m = part[0][idx]+part[1][idx]+part[2][idx]+part[3][idx];
    atomicAdd(&xm[(n*64+cc)*25+v], m*(1.f/256.f));
  }
}

// ---------- kp ----------
__global__ __launch_bounds__(64) void kp(const float* __restrict__ xm, const float* __restrict__ w2,
                                         const float* __restrict__ b2p, const float* __restrict__ Ab,
                                         float* __restrict__ p, float* __restrict__ rsA){
  const int c = blockIdx.x, n = blockIdx.y, lane = threadIdx.x;
  __shared__ float sc[32];
  __shared__ float red[2];
  float neg = 0.f;
  if (lane < 25){
    float acc = b2p[c];
    for (int k = 0; k < 64; k++) acc += w2[c*64 + k] * xm[(n*64 + k)*25 + lane];
    neg = -acc;
    sc[lane] = neg;
  }
  __syncthreads();
  if (lane == 0){
    float m = sc[0];
    for (int i = 1; i < 25; i++) m = fmaxf(m, sc[i]);
    red[0] = m;
  }
  __syncthreads();
  float e = 0.f;
  if (lane < 25){ e = expf(neg - red[0]); sc[lane] = e; }
  __syncthreads();
  if (lane == 0){
    float ssum = 0.f;
    for (int i = 0; i < 25; i++) ssum += sc[i];
    red[1] = ssum;
  }
  __syncthreads();
  if (lane < 25) p[(n*32 + c)*25 + lane] = e / red[1];
  if (n == 0 && c == 0 && lane < 25){
    float r = 0.f;
    for (int v = 0; v < 25; v++) r += Ab[lane*25 + v];
    rsA[lane] = r;
  }
}

// ---------- ks (atomic-free; w3 staged as pre-converted bf16) ----------
__global__ __launch_bounds__(256) void ks(const u16* __restrict__ xT, const u16* __restrict__ w3b,
                                          const float* __restrict__ p, float* __restrict__ s){
  __shared__ __align__(16) char smem[53248];
  __shared__ float pL[800];
  u16* aL = (u16*)smem;
  u16* bL = (u16*)(smem + 18432);
  float* z3 = (float*)smem;
  const int xb = blockIdx.x, n = blockIdx.y, tid = threadIdx.x;
  const int x0 = xb*100, t0 = xb*4;
  const int row = tid >> 1, half = tid & 1;
  {
    short8* dst = (short8*)(aL + row*72 + half*32);
    const short8* src = (const short8*)(w3b + row*64 + half*32);
    #pragma unroll
    for (int i=0;i<4;i++) dst[i] = src[i];
  }
  {
    short8* dst = (short8*)(bL + row*72 + half*32);
    if (row < 100){
      const short8* src = (const short8*)(xT + ((size_t)n*6400 + x0 + row)*64 + half*32);
      #pragma unroll
      for (int i=0;i<4;i++) dst[i] = src[i];
    } else {
      short8 z = {0,0,0,0,0,0,0,0};
      #pragma unroll
      for (int i=0;i<4;i++) dst[i] = z;
    }
  }
  for (int i = tid; i < 800; i += 256) pL[i] = p[n*800 + i];
  __syncthreads();
  const int wave = tid>>6, lane = tid&63, q = lane>>4, l = lane&15;
  const int wr = wave>>1, wc = wave&1;
  f32x4 acc[4][4];
  #pragma unroll
  for (int i=0;i<4;i++)
    #pragma unroll
    for (int j=0;j<4;j++){ f32x4 z0 = {0.f,0.f,0.f,0.f}; acc[i][j] = z0; }
  #pragma unroll
  for (int ksi = 0; ksi < 2; ksi++){
    const int kb = ksi*32 + q*8;
    short8 af[4], bf[4];
    #pragma unroll
    for (int i=0;i<4;i++) af[i] = *(const short8*)(aL + (wr*64 + i*16 + l)*72 + kb);
    #pragma unroll
    for (int j=0;j<4;j++) bf[j] = *(const short8*)(bL + (wc*64 + j*16 + l)*72 + kb);
    #pragma unroll
    for (int i=0;i<4;i++)
      #pragma unroll
      for (int j=0;j<4;j++)
        acc[i][j] = __builtin_amdgcn_mfma_f32_16x16x32_bf16(af[i], bf[j], acc[i][j], 0, 0, 0);
  }
  __syncthreads();
  #pragma unroll
  for (int i=0;i<4;i++){
    const int co0 = wr*64 + i*16 + q*4;
    #pragma unroll
    for (int j=0;j<4;j++){
      const int colx = wc*64 + j*16 + l;
      if (colx < 100){
        #pragma unroll
        for (int r=0;r<4;r++) z3[(co0 + r)*104 + colx] = acc[i][j][r];
      }
    }
  }
  __syncthreads();
  for (int idx = tid; idx < 512; idx += 256){
    const int co = idx >> 2, tt = idx & 3;
    const float* zr = z3 + co*104 + tt*25;
    const float* pr = pL + (co & 31)*25;
    float acc2 = 0.f;
    #pragma unroll
    for (int v=0; v<25; v++) acc2 += zr[v]*pr[v];
    s[((size_t)n*128 + co)*256 + t0 + tt] = acc2;
  }
}

// ---------- ky v2.1: transposed h-write through LDS ----------
// R11 post-mortem: v2's final copy reused kprep's 64-u16-row idiom on 128-u16 h
// rows -> copied exactly HALF of each row (4x short8 per half instead of 8),
// leaving stale garbage in u16 cols 32..63 / 96..127 -> absmax 2.45. Fix: 8
// iterations. Write side verified complete (co,colx both cover 0..127).
__global__ __launch_bounds__(256) void ky(const u16* __restrict__ xA, const u16* __restrict__ w4b,
      const float* __restrict__ s, const float* __restrict__ b3, const float* __restrict__ b4,
      const float* __restrict__ g1, const float* __restrict__ bb1, const float* __restrict__ m1,
      const float* __restrict__ v1, const float* __restrict__ rsA, u16* __restrict__ h){
  __shared__ __align__(16) char smem[36864];   // aL | bL ; reused as hT[128*136]
  u16* aL = (u16*)smem;
  u16* bL = (u16*)(smem + 18432);
  u16* hT = (u16*)smem;
  __shared__ float A0[128], A1[128], A2[128];
  __shared__ float sF[1024];
  __shared__ float rs[32];
  const int xb = blockIdx.x, n = blockIdx.y, tid = threadIdx.x;
  const int x0 = xb*128, tlo = x0/25;
  const int row = tid >> 1, half = tid & 1;
  {
    short8* dst = (short8*)(aL + row*72 + half*32);
    const short8* src = (const short8*)(w4b + row*64 + half*32);
    #pragma unroll
    for (int i=0;i<4;i++) dst[i] = src[i];
  }
  {
    const short8* src = (const short8*)(xA + ((size_t)n*6400 + x0 + row)*64 + half*32);
    short8* dst = (short8*)(bL + row*72 + half*32);
    #pragma unroll
    for (int i=0;i<4;i++) dst[i] = src[i];
  }
  if (tid < 128){
    const float scv = g1[tid] * rsqrtf(v1[tid] + 1e-5f);
    A0[tid] = scv;
    A1[tid] = scv * b4[tid];
    A2[tid] = bb1[tid] - m1[tid] * scv;
  }
  if (tid < 32) rs[tid] = (tid < 25) ? rsA[tid] : 0.f;
  __syncthreads();
  for (int idx = tid; idx < 1024; idx += 256){
    const int co = idx >> 3, tt = idx & 7;
    const int t = tlo + tt;
    const float sv = (t < 256) ? s[((size_t)n*128 + co)*256 + t] : 0.f;
    sF[idx] = A0[co] * (sv + b3[co]) + A2[co];
  }
  const int wave = tid>>6, lane = tid&63, q = lane>>4, l = lane&15;
  const int wr = wave>>1, wc = wave&1;
  f32x4 acc[4][4];
  #pragma unroll
  for (int i=0;i<4;i++)
    #pragma unroll
    for (int j=0;j<4;j++){ f32x4 z0 = {0.f,0.f,0.f,0.f}; acc[i][j] = z0; }
  #pragma unroll
  for (int ksi = 0; ksi < 2; ksi++){
    const int kb = ksi*32 + q*8;
    short8 af[4], bf[4];
    #pragma unroll
    for (int i=0;i<4;i++) af[i] = *(const short8*)(aL + (wr*64 + i*16 + l)*72 + kb);
    #pragma unroll
    for (int j=0;j<4;j++) bf[j] = *(const short8*)(bL + (wc*64 + j*16 + l)*72 + kb);
    #pragma unroll
    for (int i=0;i<4;i++)
      #pragma unroll
      for (int j=0;j<4;j++)
        acc[i][j] = __builtin_amdgcn_mfma_f32_16x16x32_bf16(af[i], bf[j], acc[i][j], 0, 0, 0);
  }
  __syncthreads();   // aL/bL dead from here; hT reuses the region
  #pragma unroll
  for (int i=0;i<4;i++){
    const int co0 = wr*64 + i*16 + q*4;
    #pragma unroll
    for (int j=0;j<4;j++){
      const int colx = wc*64 + j*16 + l;
      const int xg = x0 + colx;
      const int u = xg % 25, tt = xg/25 - tlo;
      const float rsu = rs[u];
      u64 pk = 0;
      #pragma unroll
      for (int r=0;r<4;r++){
        const int co = co0 + r;
        float y = A0[co]*acc[i][j][r] + A1[co]*rsu + sF[co*8 + tt];
        y = fmaxf(y, 0.f);
        pk |= ((u64)f2bu(y)) << (16*r);
      }
      *(u64*)(hT + colx*136 + co0) = pk;
    }
  }
  __syncthreads();
  {
    // coalesced h-row store: 128 u16/row; each (r2,h2) covers 64 u16 = 8x short8
    const int r2 = tid >> 1, h2 = tid & 1;
    const short8* src = (const short8*)(hT + r2*136 + h2*64);
    short8* dst = (short8*)(h + ((size_t)n*6600 + x0 + r2 + 100)*128 + h2*64);
    #pragma unroll
    for (int i=0;i<8;i++) dst[i] = src[i];
  }
}

// ---------- ktcn v7: streamed hW stage, counted vmcnt barriers (measured 105 us) ----------
__global__ __launch_bounds__(512, 2) void ktcn(const u16* __restrict__ h, const u16* __restrict__ wtb,
      const u16* __restrict__ wrb, const u16* __restrict__ xT,
      const float* __restrict__ e0g, const float* __restrict__ e1g,
      float* __restrict__ out){
  // LDS: [0,83968) hW 328 rows x 128 u16 (chunk-swizzled); [83968,116736) Abuf0; [116736,149504) Abuf1
  __shared__ __align__(16) char smem[149504];
  u16* hW = (u16*)smem;
  u16* Ab0 = (u16*)(smem + 83968);
  u16* Ab1 = (u16*)(smem + 116736);
  const int xb = blockIdx.x, n = blockIdx.y, tid = threadIdx.x;
  const int x0 = xb*128;
  const int wave = tid>>6, lane = tid&63, q = lane>>4, l = lane&15;
  const int wr2 = wave>>2, wc = wave&3;   // 2x4 wave grid: 64 co x 32 colx per wave
  const u16* hbase = h + ((size_t)n*6600 + x0)*128;
  const u16* xtb = xT + ((size_t)n*6400 + x0)*64;

  // epilogue scale/shift into regs (oldest in FIFO, drained at B_pre)
  f32x4 e0r[4], e1r[4];
  #pragma unroll
  for (int i=0;i<4;i++){
    const int co0 = wr2*64 + i*16 + q*4;
    e0r[i] = *(const f32x4*)(e0g + co0);
    e1r[i] = *(const f32x4*)(e1g + co0);
  }

  // p1: hW rows 0..127 (its 0..3)
  #pragma unroll
  for (int it = 0; it < 4; ++it){
    const int ci = it*512 + tid;
    const int r = ci >> 4, c = ci & 15;
    gll16(hbase + r*128 + ((c ^ (r & 15))<<3), hW + ((it*512 + wave*64)<<3));
  }
  // A0 (tap 0 weights)
  #pragma unroll
  for (int it = 0; it < 4; ++it){
    const int ci = it*512 + tid;
    const int r = ci >> 4, c = ci & 15;
    gll16(wtb + r*128 + ((c ^ (r & 15))<<3), Ab0 + ((it*512 + wave*64)<<3));
  }
  // A1 (tap 1 weights)
  #pragma unroll
  for (int it = 0; it < 4; ++it){
    const int ci = it*512 + tid;
    const int r = ci >> 4, c = ci & 15;
    gll16(wtb + 16384 + r*128 + ((c ^ (r & 15))<<3), Ab1 + ((it*512 + wave*64)<<3));
  }
  // it4, it5: hW rows 128..191 (covers taps 1,2 needs)
  #pragma unroll
  for (int it = 4; it < 6; ++it){
    const int ci = it*512 + tid;
    const int r = ci >> 4, c = ci & 15;
    gll16(hbase + r*128 + ((c ^ (r & 15))<<3), hW + ((it*512 + wave*64)<<3));
  }

  f32x4 acc[4][2];
  #pragma unroll
  for (int i=0;i<4;i++)
    #pragma unroll
    for (int j=0;j<2;j++){ f32x4 z0 = {0.f,0.f,0.f,0.f}; acc[i][j] = z0; }

  // B_pre: require E + p1 + A0 complete; allow A1 + it4 + it5 (6 newest ops/thread) in flight
  asm volatile("s_waitcnt vmcnt(6) lgkmcnt(0)" ::: "memory");
  __builtin_amdgcn_s_barrier();
  __builtin_amdgcn_sched_barrier(0);

  #pragma unroll 1
  for (int dt = 0; dt <= 9; ++dt){
    // A-prefetch: taps 1..7 issue A(dt+1) into the buffer not being read this tap
    if (dt >= 1 && dt <= 7){
      const u16* gA = wtb + (dt+1)*16384;
      u16* dA = ((dt+1) & 1) ? Ab1 : Ab0;
      #pragma unroll
      for (int it = 0; it < 4; ++it){
        const int ci = it*512 + tid;
        const int r = ci >> 4, c = ci & 15;
        gll16(gA + r*128 + ((c ^ (r & 15))<<3), dA + ((it*512 + wave*64)<<3));
      }
    } else if (dt == 8){
      // residual operands into Ab1: wrb (16 KB) then xT tile (16 KB)
      #pragma unroll
      for (int it = 0; it < 2; ++it){
        const int ci = it*512 + tid;
        const int r = ci >> 3, c = ci & 7;
        gll16(wrb + r*64 + ((c ^ (r & 7))<<3), Ab1 + ((it*512 + wave*64)<<3));
      }
      #pragma unroll
      for (int it = 0; it < 2; ++it){
        const int ci = it*512 + tid;
        const int r = ci >> 3, c = ci & 7;
        gll16(xtb + r*64 + ((c ^ (r & 7))<<3), Ab1 + 8192 + ((it*512 + wave*64)<<3));
      }
    }
    // streamed hW remainder: taps 1..4 issue it6..it9 (+tail at dt=4)
    if (dt >= 1 && dt <= 4){
      const int it = 5 + dt;   // 6..9, rows 192..319
      const int ci = it*512 + tid;
      const int r = ci >> 4, c = ci & 15;
      gll16(hbase + r*128 + ((c ^ (r & 15))<<3), hW + ((it*512 + wave*64)<<3));
      if (dt == 4 && tid < 128){  // tail rows 320..327 (waves 0,1)
        const int ci2 = 5120 + tid;
        const int r2 = ci2 >> 4, c2 = ci2 & 15;
        gll16(hbase + r2*128 + ((c2 ^ (r2 & 15))<<3), hW + ((5120 + wave*64)<<3));
      }
    }
    // compute
    if (dt < 9){
      const u16* A = (dt & 1) ? Ab1 : Ab0;
      #pragma unroll
      for (int ksi = 0; ksi < 4; ksi++){
        const int c0 = ksi*4 + q;
        short8 af[4], bf[2];
        #pragma unroll
        for (int i=0;i<4;i++){
          const int r = wr2*64 + i*16 + l;
          af[i] = *(const short8*)(A + (((r<<4) + (c0 ^ (r & 15)))<<3));
        }
        #pragma unroll
        for (int j=0;j<2;j++){
          const int r = dt*25 + wc*32 + j*16 + l;
          bf[j] = *(const short8*)(hW + (((r<<4) + (c0 ^ (r & 15)))<<3));
        }
        #pragma unroll
        for (int i=0;i<4;i++)
          #pragma unroll
          for (int j=0;j<2;j++)
            acc[i][j] = __builtin_amdgcn_mfma_f32_16x16x32_bf16(af[i], bf[j], acc[i][j], 0, 0, 0);
      }
    } else {
      // residual tap: K=64, A=wrb (pre-scaled), B=xT tile, both in Ab1
      const u16* A = Ab1;
      const u16* B = Ab1 + 8192;
      #pragma unroll
      for (int ksi = 0; ksi < 2; ksi++){
        const int c0 = ksi*4 + q;
        short8 af[4], bf[2];
        #pragma unroll
        for (int i=0;i<4;i++){
          const int r = wr2*64 + i*16 + l;
          af[i] = *(const short8*)(A + (((r<<3) + (c0 ^ (r & 7)))<<3));
        }
        #pragma unroll
        for (int j=0;j<2;j++){
          const int r = wc*32 + j*16 + l;
          bf[j] = *(const short8*)(B + (((r<<3) + (c0 ^ (r & 7)))<<3));
        }
        #pragma unroll
        for (int i=0;i<4;i++)
          #pragma unroll
          for (int j=0;j<2;j++)
            acc[i][j] = __builtin_amdgcn_mfma_f32_16x16x32_bf16(af[i], bf[j], acc[i][j], 0, 0, 0);
      }
    }
    // barrier: counted for dt<=4; plain syncthreads from dt=5
    if (dt < 9){
      if (dt <= 4){
        asm volatile("s_waitcnt vmcnt(1) lgkmcnt(0)" ::: "memory");
        __builtin_amdgcn_s_barrier();
        __builtin_amdgcn_sched_barrier(0);
      } else {
        __syncthreads();
      }
    }
  }

  // ---- epilogue: scale + relu via reg-held e0/e1, direct stores ----
  #pragma unroll
  for (int i=0;i<4;i++){
    const int co0 = wr2*64 + i*16 + q*4;
    #pragma unroll
    for (int j=0;j<2;j++){
      const int colx = wc*32 + j*16 + l;
      #pragma unroll
      for (int r=0;r<4;r++){
        const float yv = e0r[i][r]*acc[i][j][r] + e1r[i][r];
        out[((size_t)n*128 + co0 + r)*6400 + x0 + colx] = fmaxf(yv, 0.f);
      }
    }
  }
}

extern "C" void kernel_launch(void* const* d_in, const int* in_sizes, int n_in,
                              void* d_out, int out_size, void* d_ws, size_t ws_size,
                              hipStream_t stream){
  const float* x   = (const float*)d_in[0];
  const float* Ab  = (const float*)d_in[1];
  // d_in[2],d_in[3] = w1,b1: dead (softmax cancellation)
  const float* w2  = (const float*)d_in[4];
  const float* b2p = (const float*)d_in[5];
  const float* w3  = (const float*)d_in[6];
  const float* b3  = (const float*)d_in[7];
  const float* w4  = (const float*)d_in[8];
  const float* b4  = (const float*)d_in[9];
  const float* g1  = (const float*)d_in[10];
  const float* bb1 = (const float*)d_in[11];
  const float* m1  = (const float*)d_in[12];
  const float* v1  = (const float*)d_in[13];
  const float* wt  = (const float*)d_in[14];
  const float* bt  = (const float*)d_in[15];
  const float* g2  = (const float*)d_in[16];
  const float* bb2 = (const float*)d_in[17];
  const float* m2  = (const float*)d_in[18];
  const float* v2  = (const float*)d_in[19];
  const float* wrw = (const float*)d_in[20];
  const float* brb = (const float*)d_in[21];
  const float* gr  = (const float*)d_in[22];
  const float* bbr = (const float*)d_in[23];
  const float* mr  = (const float*)d_in[24];
  const float* vr  = (const float*)d_in[25];
  float* out = (float*)d_out;

  char* ws = (char*)d_ws;
  float* xm  = (float*)(ws);               // 204,800 B
  float* p   = (float*)(ws + 204800);      // 102,400 B
  float* rsA = (float*)(ws + 307200);      // 512 B
  float* s   = (float*)(ws + 307712);      // 4,194,304 B
  u16* xT    = (u16*)(ws + 4502016);       // 26,214,400 B  [n][6400][64]
  u16* xA    = (u16*)(ws + 30716416);      // 26,214,400 B  [n][6400][64]
  u16* h     = (u16*)(ws + 56930816);      // 54,067,200 B  [n][6600][128]
  u16* wtb   = (u16*)(ws + 110998016);     // 294,912 B     [9][128][128]
  u16* wrb   = (u16*)(ws + 111292928);     // 16,384 B      [128][64]
  u16* w3b   = (u16*)(ws + 111309312);     // 16,384 B      [128][64]
  u16* w4b   = (u16*)(ws + 111325696);     // 16,384 B      [128][64]
  float* e0  = (float*)(ws + 111342080);   // 512 B
  float* e1  = (float*)(ws + 111342592);   // 512 B

  kaux<<<787, 256, 0, stream>>>(wt, wrw, g2, v2, gr, vr, w3, w4, bt, bb2, m2, bbr, mr, brb,
                                xm, wtb, wrb, w3b, w4b, e0, e1, h);
  kprep2<<<dim3(32,32), 256, 0, stream>>>(x, Ab, xT, xA);
  kmean<<<dim3(8,32), 256, 0, stream>>>(xT, xm);
  kp<<<dim3(32,32), 64, 0, stream>>>(xm, w2, b2p, Ab, p, rsA);
  ks<<<dim3(64,32), 256, 0, stream>>>(xT, w3b, p, s);
  ky<<<dim3(50,32), 256, 0, stream>>>(xA, w4b, s, b3, b4, g1, bb1, m1, v1, rsA, h);
  ktcn<<<dim3(50,32), 512, 0, stream>>>(h, wtb, wrb, xT, e0, e1, out);
}

// Round 13
// 393.640 us; speedup vs baseline: 1.0205x; 1.0089x over previous
//
#include <hip/hip_runtime.h>
#include <hip/hip_bf16.h>

typedef unsigned short u16;
typedef unsigned int u32;
typedef unsigned long long u64;
typedef __attribute__((ext_vector_type(8))) short short8;
typedef __attribute__((ext_vector_type(4))) float f32x4;

#define DI __device__ __forceinline__

DI float b2f(u16 v){ u32 u = ((u32)v) << 16; float f; __builtin_memcpy(&f, &u, 4); return f; }
DI u16 f2bu(float f){ __hip_bfloat16 h = __float2bfloat16(f); u16 u; __builtin_memcpy(&u, &h, 2); return u; }

// async 16B global->LDS DMA; LDS dest = wave-uniform base + lane*16
DI void gll16(const u16* g, u16* l){
  __builtin_amdgcn_global_load_lds((const __attribute__((address_space(1))) void*)g,
                                   (__attribute__((address_space(3))) void*)l, 16, 0, 0);
}

// ---------- kaux: fused kzero + kwt + kwr(wrb,w3b,w4b,e0,e1) + khpad ----------
__global__ __launch_bounds__(256) void kaux(const float* __restrict__ wt, const float* __restrict__ wrw,
      const float* __restrict__ g2, const float* __restrict__ v2,
      const float* __restrict__ gr, const float* __restrict__ vr,
      const float* __restrict__ w3, const float* __restrict__ w4,
      const float* __restrict__ bt, const float* __restrict__ bb2, const float* __restrict__ m2,
      const float* __restrict__ bbr, const float* __restrict__ mr, const float* __restrict__ brb,
      float* __restrict__ xm, u16* __restrict__ wtb, u16* __restrict__ wrb,
      u16* __restrict__ w3b, u16* __restrict__ w4b,
      float* __restrict__ e0, float* __restrict__ e1, u16* __restrict__ h){
  const int b = blockIdx.x, tid = threadIdx.x;
  if (b < 50){                       // xm = 0
    const int i = b*1024 + tid*4;
    float4 z = {0.f,0.f,0.f,0.f};
    *(float4*)(xm + i) = z;
  } else if (b < 626){               // wtb[dt][co][ci] = bf16(wt[co][ci][dt])
    const int o = (b-50)*256 + tid;
    const int dt = o >> 14, rem = o & 16383;
    wtb[o] = f2bu(wt[rem*9 + dt]);
  } else if (b < 658){               // wrb = wr * R0/E0
    const int o = (b-626)*256 + tid;
    const int co = o >> 6;
    const float E0 = g2[co]*rsqrtf(v2[co]+1e-5f);
    const float R0 = gr[co]*rsqrtf(vr[co]+1e-5f);
    wrb[o] = f2bu(wrw[o]*R0/E0);
  } else if (b < 690){               // w3b
    const int o = (b-658)*256 + tid;
    w3b[o] = f2bu(w3[o]);
  } else if (b < 722){               // w4b
    const int o = (b-690)*256 + tid;
    w4b[o] = f2bu(w4[o]);
  } else if (b < 786){               // h padding rows
    const int j = b - 722, n = j >> 1, side = j & 1;
    short8* base = (short8*)(h + ((size_t)n*6600 + (side ? 6500 : 0))*128);
    short8 z = {0,0,0,0,0,0,0,0};
    for (int i = tid; i < 1600; i += 256) base[i] = z;
  } else {                            // e0/e1 epilogue constants
    if (tid < 128){
      const float scv2 = g2[tid]*rsqrtf(v2[tid]+1e-5f);
      const float scvr = gr[tid]*rsqrtf(vr[tid]+1e-5f);
      e0[tid] = scv2;
      e1[tid] = scv2*bt[tid] + bb2[tid] - m2[tid]*scv2
              + (bbr[tid] - mr[tid]*scvr + scvr*brb[tid]);
    }
  }
}

// ---------- kprep2 v2: 512 threads (mix split by k-half -> 2x occupancy, half serial depth) ----------
__global__ __launch_bounds__(512) void kprep2(const float* __restrict__ x, const float* __restrict__ Ab,
                                              u16* __restrict__ xT, u16* __restrict__ xA){
  __shared__ float xl[200*68];
  __shared__ float al[625];
  const int tc = blockIdx.x, n = blockIdx.y, tid = threadIdx.x;
  const int x0t = tc * 200;
  for (int i = tid; i < 625; i += 512) al[i] = Ab[i];
  // load x tile fp32: 64 ci rows x 200 cols, float4 (16B/lane) coalesced
  for (int idx = tid; idx < 3200; idx += 512){
    const int ci = idx / 50, c4 = idx - ci*50;
    const float4 f = *(const float4*)(x + ((size_t)(n*64+ci))*6400 + x0t + c4*4);
    float* d = xl + (c4*4)*68 + ci;
    d[0] = f.x; d[68] = f.y; d[136] = f.z; d[204] = f.w;
  }
  __syncthreads();
  // xT store: bf16 pack, u64 (4 u16) per iter, coalesced
  for (int idx = tid; idx < 3200; idx += 512){
    const int r = idx >> 4, k4 = (idx & 15) << 2;
    const float* src = xl + r*68 + k4;
    u64 pk = (u64)f2bu(src[0]) | ((u64)f2bu(src[1])<<16)
           | ((u64)f2bu(src[2])<<32) | ((u64)f2bu(src[3])<<48);
    *(u64*)(xT + ((size_t)n*6400 + x0t + r)*64 + k4) = pk;
  }
  // A-mix: 400 units = 200 rows x 2 k-halves; acc[32] per thread
  if (tid < 400){
    const int r = tid >> 1, kh = tid & 1;
    const int t_ = r / 25, u = r % 25;
    float acc[32];
    #pragma unroll
    for (int k = 0; k < 32; k++) acc[k] = 0.f;
    const float* arow = al + u*25;
    for (int v = 0; v < 25; v++){
      const float a = arow[v];
      const float* xr = xl + (t_*25 + v)*68 + kh*32;
      #pragma unroll
      for (int k = 0; k < 32; k++) acc[k] += a * xr[k];
    }
    u16* dst = xA + ((size_t)n*6400 + x0t + r)*64 + kh*32;
    #pragma unroll
    for (int k = 0; k < 32; k += 4){
      u64 pk = (u64)f2bu(acc[k]) | ((u64)f2bu(acc[k+1])<<16)
             | ((u64)f2bu(acc[k+2])<<32) | ((u64)f2bu(acc[k+3])<<48);
      *(u64*)(dst + k) = pk;
    }
  }
}

// ---------- kmean v2: chunked LDS staging, coalesced short8 loads ----------
// R12: old kmean = 256 blocks x 4 waves/CU issuing 100 scalar stride-128B u16
// loads/lane — latency-bound at 12.5% occupancy. v2: stage 200 rows/chunk via
// coalesced short8 (16B/lane), accumulate (v,c) sums from LDS in registers
// across 4 chunks; same 8-way-contention atomics (410K total).
__global__ __launch_bounds__(256) void kmean(const u16* __restrict__ xT, float* __restrict__ xm){
  __shared__ u16 tile[200*72];
  const int seg = blockIdx.x, n = blockIdx.y, tid = threadIdx.x;
  float acc[7];
  #pragma unroll
  for (int j=0;j<7;j++) acc[j] = 0.f;
  for (int ch = 0; ch < 4; ++ch){
    const int r0 = seg*800 + ch*200;
    for (int idx = tid; idx < 1600; idx += 256){
      const int row = idx >> 3, part = idx & 7;
      *(short8*)(tile + row*72 + part*8) =
        *(const short8*)(xT + ((size_t)n*6400 + r0 + row)*64 + part*8);
    }
    __syncthreads();
    #pragma unroll
    for (int j=0;j<7;j++){
      const int idx = tid + j*256;
      if (idx < 1600){
        const int v = idx >> 6, c = idx & 63;
        float s2 = 0.f;
        #pragma unroll
        for (int t=0;t<8;t++) s2 += b2f(tile[(t*25+v)*72 + c]);
        acc[j] += s2;
      }
    }
    __syncthreads();
  }
  #pragma unroll
  for (int j=0;j<7;j++){
    const int idx = tid + j*256;
    if (idx < 1600){
      const int v = idx >> 6, c = idx & 63;
      atomicAdd(&xm[(n*64+c)*25+v], acc[j]*(1.f/256.f));
    }
  }
}

// ---------- kp ----------
__global__ __launch_bounds__(64) void kp(const float* __restrict__ xm, const float* __restrict__ w2,
                                         const float* __restrict__ b2p, const float* __restrict__ Ab,
                                         float* __restrict__ p, float* __restrict__ rsA){
  const int c = blockIdx.x, n = blockIdx.y, lane = threadIdx.x;
  __shared__ float sc[32];
  __shared__ float red[2];
  float neg = 0.f;
  if (lane < 25){
    float acc = b2p[c];
    for (int k = 0; k < 64; k++) acc += w2[c*64 + k] * xm[(n*64 + k)*25 + lane];
    neg = -acc;
    sc[lane] = neg;
  }
  __syncthreads();
  if (lane == 0){
    float m = sc[0];
    for (int i = 1; i < 25; i++) m = fmaxf(m, sc[i]);
    red[0] = m;
  }
  __syncthreads();
  float e = 0.f;
  if (lane < 25){ e = expf(neg - red[0]); sc[lane] = e; }
  __syncthreads();
  if (lane == 0){
    float ssum = 0.f;
    for (int i = 0; i < 25; i++) ssum += sc[i];
    red[1] = ssum;
  }
  __syncthreads();
  if (lane < 25) p[(n*32 + c)*25 + lane] = e / red[1];
  if (n == 0 && c == 0 && lane < 25){
    float r = 0.f;
    for (int v = 0; v < 25; v++) r += Ab[lane*25 + v];
    rsA[lane] = r;
  }
}

// ---------- ks (atomic-free; w3 staged as pre-converted bf16) ----------
__global__ __launch_bounds__(256) void ks(const u16* __restrict__ xT, const u16* __restrict__ w3b,
                                          const float* __restrict__ p, float* __restrict__ s){
  __shared__ __align__(16) char smem[53248];
  __shared__ float pL[800];
  u16* aL = (u16*)smem;
  u16* bL = (u16*)(smem + 18432);
  float* z3 = (float*)smem;
  const int xb = blockIdx.x, n = blockIdx.y, tid = threadIdx.x;
  const int x0 = xb*100, t0 = xb*4;
  const int row = tid >> 1, half = tid & 1;
  {
    short8* dst = (short8*)(aL + row*72 + half*32);
    const short8* src = (const short8*)(w3b + row*64 + half*32);
    #pragma unroll
    for (int i=0;i<4;i++) dst[i] = src[i];
  }
  {
    short8* dst = (short8*)(bL + row*72 + half*32);
    if (row < 100){
      const short8* src = (const short8*)(xT + ((size_t)n*6400 + x0 + row)*64 + half*32);
      #pragma unroll
      for (int i=0;i<4;i++) dst[i] = src[i];
    } else {
      short8 z = {0,0,0,0,0,0,0,0};
      #pragma unroll
      for (int i=0;i<4;i++) dst[i] = z;
    }
  }
  for (int i = tid; i < 800; i += 256) pL[i] = p[n*800 + i];
  __syncthreads();
  const int wave = tid>>6, lane = tid&63, q = lane>>4, l = lane&15;
  const int wr = wave>>1, wc = wave&1;
  f32x4 acc[4][4];
  #pragma unroll
  for (int i=0;i<4;i++)
    #pragma unroll
    for (int j=0;j<4;j++){ f32x4 z0 = {0.f,0.f,0.f,0.f}; acc[i][j] = z0; }
  #pragma unroll
  for (int ksi = 0; ksi < 2; ksi++){
    const int kb = ksi*32 + q*8;
    short8 af[4], bf[4];
    #pragma unroll
    for (int i=0;i<4;i++) af[i] = *(const short8*)(aL + (wr*64 + i*16 + l)*72 + kb);
    #pragma unroll
    for (int j=0;j<4;j++) bf[j] = *(const short8*)(bL + (wc*64 + j*16 + l)*72 + kb);
    #pragma unroll
    for (int i=0;i<4;i++)
      #pragma unroll
      for (int j=0;j<4;j++)
        acc[i][j] = __builtin_amdgcn_mfma_f32_16x16x32_bf16(af[i], bf[j], acc[i][j], 0, 0, 0);
  }
  __syncthreads();
  #pragma unroll
  for (int i=0;i<4;i++){
    const int co0 = wr*64 + i*16 + q*4;
    #pragma unroll
    for (int j=0;j<4;j++){
      const int colx = wc*64 + j*16 + l;
      if (colx < 100){
        #pragma unroll
        for (int r=0;r<4;r++) z3[(co0 + r)*104 + colx] = acc[i][j][r];
      }
    }
  }
  __syncthreads();
  for (int idx = tid; idx < 512; idx += 256){
    const int co = idx >> 2, tt = idx & 3;
    const float* zr = z3 + co*104 + tt*25;
    const float* pr = pL + (co & 31)*25;
    float acc2 = 0.f;
    #pragma unroll
    for (int v=0; v<25; v++) acc2 += zr[v]*pr[v];
    s[((size_t)n*128 + co)*256 + t0 + tt] = acc2;
  }
}

// ---------- ky v2.1: transposed h-write through LDS ----------
__global__ __launch_bounds__(256) void ky(const u16* __restrict__ xA, const u16* __restrict__ w4b,
      const float* __restrict__ s, const float* __restrict__ b3, const float* __restrict__ b4,
      const float* __restrict__ g1, const float* __restrict__ bb1, const float* __restrict__ m1,
      const float* __restrict__ v1, const float* __restrict__ rsA, u16* __restrict__ h){
  __shared__ __align__(16) char smem[36864];   // aL | bL ; reused as hT[128*136]
  u16* aL = (u16*)smem;
  u16* bL = (u16*)(smem + 18432);
  u16* hT = (u16*)smem;
  __shared__ float A0[128], A1[128], A2[128];
  __shared__ float sF[1024];
  __shared__ float rs[32];
  const int xb = blockIdx.x, n = blockIdx.y, tid = threadIdx.x;
  const int x0 = xb*128, tlo = x0/25;
  const int row = tid >> 1, half = tid & 1;
  {
    short8* dst = (short8*)(aL + row*72 + half*32);
    const short8* src = (const short8*)(w4b + row*64 + half*32);
    #pragma unroll
    for (int i=0;i<4;i++) dst[i] = src[i];
  }
  {
    const short8* src = (const short8*)(xA + ((size_t)n*6400 + x0 + row)*64 + half*32);
    short8* dst = (short8*)(bL + row*72 + half*32);
    #pragma unroll
    for (int i=0;i<4;i++) dst[i] = src[i];
  }
  if (tid < 128){
    const float scv = g1[tid] * rsqrtf(v1[tid] + 1e-5f);
    A0[tid] = scv;
    A1[tid] = scv * b4[tid];
    A2[tid] = bb1[tid] - m1[tid] * scv;
  }
  if (tid < 32) rs[tid] = (tid < 25) ? rsA[tid] : 0.f;
  __syncthreads();
  for (int idx = tid; idx < 1024; idx += 256){
    const int co = idx >> 3, tt = idx & 7;
    const int t = tlo + tt;
    const float sv = (t < 256) ? s[((size_t)n*128 + co)*256 + t] : 0.f;
    sF[idx] = A0[co] * (sv + b3[co]) + A2[co];
  }
  const int wave = tid>>6, lane = tid&63, q = lane>>4, l = lane&15;
  const int wr = wave>>1, wc = wave&1;
  f32x4 acc[4][4];
  #pragma unroll
  for (int i=0;i<4;i++)
    #pragma unroll
    for (int j=0;j<4;j++){ f32x4 z0 = {0.f,0.f,0.f,0.f}; acc[i][j] = z0; }
  #pragma unroll
  for (int ksi = 0; ksi < 2; ksi++){
    const int kb = ksi*32 + q*8;
    short8 af[4], bf[4];
    #pragma unroll
    for (int i=0;i<4;i++) af[i] = *(const short8*)(aL + (wr*64 + i*16 + l)*72 + kb);
    #pragma unroll
    for (int j=0;j<4;j++) bf[j] = *(const short8*)(bL + (wc*64 + j*16 + l)*72 + kb);
    #pragma unroll
    for (int i=0;i<4;i++)
      #pragma unroll
      for (int j=0;j<4;j++)
        acc[i][j] = __builtin_amdgcn_mfma_f32_16x16x32_bf16(af[i], bf[j], acc[i][j], 0, 0, 0);
  }
  __syncthreads();   // aL/bL dead from here; hT reuses the region
  #pragma unroll
  for (int i=0;i<4;i++){
    const int co0 = wr*64 + i*16 + q*4;
    #pragma unroll
    for (int j=0;j<4;j++){
      const int colx = wc*64 + j*16 + l;
      const int xg = x0 + colx;
      const int u = xg % 25, tt = xg/25 - tlo;
      const float rsu = rs[u];
      u64 pk = 0;
      #pragma unroll
      for (int r=0;r<4;r++){
        const int co = co0 + r;
        float y = A0[co]*acc[i][j][r] + A1[co]*rsu + sF[co*8 + tt];
        y = fmaxf(y, 0.f);
        pk |= ((u64)f2bu(y)) << (16*r);
      }
      *(u64*)(hT + colx*136 + co0) = pk;
    }
  }
  __syncthreads();
  {
    // coalesced h-row store: 128 u16/row; each (r2,h2) covers 64 u16 = 8x short8
    const int r2 = tid >> 1, h2 = tid & 1;
    const short8* src = (const short8*)(hT + r2*136 + h2*64);
    short8* dst = (short8*)(h + ((size_t)n*6600 + x0 + r2 + 100)*128 + h2*64);
    #pragma unroll
    for (int i=0;i<8;i++) dst[i] = src[i];
  }
}

// ---------- ktcn v7: streamed hW stage, counted vmcnt barriers (measured 105-113 us) ----------
__global__ __launch_bounds__(512, 2) void ktcn(const u16* __restrict__ h, const u16* __restrict__ wtb,
      const u16* __restrict__ wrb, const u16* __restrict__ xT,
      const float* __restrict__ e0g, const float* __restrict__ e1g,
      float* __restrict__ out){
  // LDS: [0,83968) hW 328 rows x 128 u16 (chunk-swizzled); [83968,116736) Abuf0; [116736,149504) Abuf1
  __shared__ __align__(16) char smem[149504];
  u16* hW = (u16*)smem;
  u16* Ab0 = (u16*)(smem + 83968);
  u16* Ab1 = (u16*)(smem + 116736);
  const int xb = blockIdx.x, n = blockIdx.y, tid = threadIdx.x;
  const int x0 = xb*128;
  const int wave = tid>>6, lane = tid&63, q = lane>>4, l = lane&15;
  const int wr2 = wave>>2, wc = wave&3;   // 2x4 wave grid: 64 co x 32 colx per wave
  const u16* hbase = h + ((size_t)n*6600 + x0)*128;
  const u16* xtb = xT + ((size_t)n*6400 + x0)*64;

  // epilogue scale/shift into regs (oldest in FIFO, drained at B_pre)
  f32x4 e0r[4], e1r[4];
  #pragma unroll
  for (int i=0;i<4;i++){
    const int co0 = wr2*64 + i*16 + q*4;
    e0r[i] = *(const f32x4*)(e0g + co0);
    e1r[i] = *(const f32x4*)(e1g + co0);
  }

  // p1: hW rows 0..127 (its 0..3)
  #pragma unroll
  for (int it = 0; it < 4; ++it){
    const int ci = it*512 + tid;
    const int r = ci >> 4, c = ci & 15;
    gll16(hbase + r*128 + ((c ^ (r & 15))<<3), hW + ((it*512 + wave*64)<<3));
  }
  // A0 (tap 0 weights)
  #pragma unroll
  for (int it = 0; it < 4; ++it){
    const int ci = it*512 + tid;
    const int r = ci >> 4, c = ci & 15;
    gll16(wtb + r*128 + ((c ^ (r & 15))<<3), Ab0 + ((it*512 + wave*64)<<3));
  }
  // A1 (tap 1 weights)
  #pragma unroll
  for (int it = 0; it < 4; ++it){
    const int ci = it*512 + tid;
    const int r = ci >> 4, c = ci & 15;
    gll16(wtb + 16384 + r*128 + ((c ^ (r & 15))<<3), Ab1 + ((it*512 + wave*64)<<3));
  }
  // it4, it5: hW rows 128..191 (covers taps 1,2 needs)
  #pragma unroll
  for (int it = 4; it < 6; ++it){
    const int ci = it*512 + tid;
    const int r = ci >> 4, c = ci & 15;
    gll16(hbase + r*128 + ((c ^ (r & 15))<<3), hW + ((it*512 + wave*64)<<3));
  }

  f32x4 acc[4][2];
  #pragma unroll
  for (int i=0;i<4;i++)
    #pragma unroll
    for (int j=0;j<2;j++){ f32x4 z0 = {0.f,0.f,0.f,0.f}; acc[i][j] = z0; }

  // B_pre: require E + p1 + A0 complete; allow A1 + it4 + it5 (6 newest ops/thread) in flight
  asm volatile("s_waitcnt vmcnt(6) lgkmcnt(0)" ::: "memory");
  __builtin_amdgcn_s_barrier();
  __builtin_amdgcn_sched_barrier(0);

  #pragma unroll 1
  for (int dt = 0; dt <= 9; ++dt){
    // A-prefetch: taps 1..7 issue A(dt+1) into the buffer not being read this tap
    if (dt >= 1 && dt <= 7){
      const u16* gA = wtb + (dt+1)*16384;
      u16* dA = ((dt+1) & 1) ? Ab1 : Ab0;
      #pragma unroll
      for (int it = 0; it < 4; ++it){
        const int ci = it*512 + tid;
        const int r = ci >> 4, c = ci & 15;
        gll16(gA + r*128 + ((c ^ (r & 15))<<3), dA + ((it*512 + wave*64)<<3));
      }
    } else if (dt == 8){
      // residual operands into Ab1: wrb (16 KB) then xT tile (16 KB)
      #pragma unroll
      for (int it = 0; it < 2; ++it){
        const int ci = it*512 + tid;
        const int r = ci >> 3, c = ci & 7;
        gll16(wrb + r*64 + ((c ^ (r & 7))<<3), Ab1 + ((it*512 + wave*64)<<3));
      }
      #pragma unroll
      for (int it = 0; it < 2; ++it){
        const int ci = it*512 + tid;
        const int r = ci >> 3, c = ci & 7;
        gll16(xtb + r*64 + ((c ^ (r & 7))<<3), Ab1 + 8192 + ((it*512 + wave*64)<<3));
      }
    }
    // streamed hW remainder: taps 1..4 issue it6..it9 (+tail at dt=4)
    if (dt >= 1 && dt <= 4){
      const int it = 5 + dt;   // 6..9, rows 192..319
      const int ci = it*512 + tid;
      const int r = ci >> 4, c = ci & 15;
      gll16(hbase + r*128 + ((c ^ (r & 15))<<3), hW + ((it*512 + wave*64)<<3));
      if (dt == 4 && tid < 128){  // tail rows 320..327 (waves 0,1)
        const int ci2 = 5120 + tid;
        const int r2 = ci2 >> 4, c2 = ci2 & 15;
        gll16(hbase + r2*128 + ((c2 ^ (r2 & 15))<<3), hW + ((5120 + wave*64)<<3));
      }
    }
    // compute
    if (dt < 9){
      const u16* A = (dt & 1) ? Ab1 : Ab0;
      #pragma unroll
      for (int ksi = 0; ksi < 4; ksi++){
        const int c0 = ksi*4 + q;
        short8 af[4], bf[2];
        #pragma unroll
        for (int i=0;i<4;i++){
          const int r = wr2*64 + i*16 + l;
          af[i] = *(const short8*)(A + (((r<<4) + (c0 ^ (r & 15)))<<3));
        }
        #pragma unroll
        for (int j=0;j<2;j++){
          const int r = dt*25 + wc*32 + j*16 + l;
          bf[j] = *(const short8*)(hW + (((r<<4) + (c0 ^ (r & 15)))<<3));
        }
        #pragma unroll
        for (int i=0;i<4;i++)
          #pragma unroll
          for (int j=0;j<2;j++)
            acc[i][j] = __builtin_amdgcn_mfma_f32_16x16x32_bf16(af[i], bf[j], acc[i][j], 0, 0, 0);
      }
    } else {
      // residual tap: K=64, A=wrb (pre-scaled), B=xT tile, both in Ab1
      const u16* A = Ab1;
      const u16* B = Ab1 + 8192;
      #pragma unroll
      for (int ksi = 0; ksi < 2; ksi++){
        const int c0 = ksi*4 + q;
        short8 af[4], bf[2];
        #pragma unroll
        for (int i=0;i<4;i++){
          const int r = wr2*64 + i*16 + l;
          af[i] = *(const short8*)(A + (((r<<3) + (c0 ^ (r & 7)))<<3));
        }
        #pragma unroll
        for (int j=0;j<2;j++){
          const int r = wc*32 + j*16 + l;
          bf[j] = *(const short8*)(B + (((r<<3) + (c0 ^ (r & 7)))<<3));
        }
        #pragma unroll
        for (int i=0;i<4;i++)
          #pragma unroll
          for (int j=0;j<2;j++)
            acc[i][j] = __builtin_amdgcn_mfma_f32_16x16x32_bf16(af[i], bf[j], acc[i][j], 0, 0, 0);
      }
    }
    // barrier: counted for dt<=4; plain syncthreads from dt=5
    if (dt < 9){
      if (dt <= 4){
        asm volatile("s_waitcnt vmcnt(1) lgkmcnt(0)" ::: "memory");
        __builtin_amdgcn_s_barrier();
        __builtin_amdgcn_sched_barrier(0);
      } else {
        __syncthreads();
      }
    }
  }

  // ---- epilogue: scale + relu via reg-held e0/e1, direct stores ----
  #pragma unroll
  for (int i=0;i<4;i++){
    const int co0 = wr2*64 + i*16 + q*4;
    #pragma unroll
    for (int j=0;j<2;j++){
      const int colx = wc*32 + j*16 + l;
      #pragma unroll
      for (int r=0;r<4;r++){
        const float yv = e0r[i][r]*acc[i][j][r] + e1r[i][r];
        out[((size_t)n*128 + co0 + r)*6400 + x0 + colx] = fmaxf(yv, 0.f);
      }
    }
  }
}

extern "C" void kernel_launch(void* const* d_in, const int* in_sizes, int n_in,
                              void* d_out, int out_size, void* d_ws, size_t ws_size,
                              hipStream_t stream){
  const float* x   = (const float*)d_in[0];
  const float* Ab  = (const float*)d_in[1];
  // d_in[2],d_in[3] = w1,b1: dead (softmax cancellation)
  const float* w2  = (const float*)d_in[4];
  const float* b2p = (const float*)d_in[5];
  const float* w3  = (const float*)d_in[6];
  const float* b3  = (const float*)d_in[7];
  const float* w4  = (const float*)d_in[8];
  const float* b4  = (const float*)d_in[9];
  const float* g1  = (const float*)d_in[10];
  const float* bb1 = (const float*)d_in[11];
  const float* m1  = (const float*)d_in[12];
  const float* v1  = (const float*)d_in[13];
  const float* wt  = (const float*)d_in[14];
  const float* bt  = (const float*)d_in[15];
  const float* g2  = (const float*)d_in[16];
  const float* bb2 = (const float*)d_in[17];
  const float* m2  = (const float*)d_in[18];
  const float* v2  = (const float*)d_in[19];
  const float* wrw = (const float*)d_in[20];
  const float* brb = (const float*)d_in[21];
  const float* gr  = (const float*)d_in[22];
  const float* bbr = (const float*)d_in[23];
  const float* mr  = (const float*)d_in[24];
  const float* vr  = (const float*)d_in[25];
  float* out = (float*)d_out;

  char* ws = (char*)d_ws;
  float* xm  = (float*)(ws);               // 204,800 B
  float* p   = (float*)(ws + 204800);      // 102,400 B
  float* rsA = (float*)(ws + 307200);      // 512 B
  float* s   = (float*)(ws + 307712);      // 4,194,304 B
  u16* xT    = (u16*)(ws + 4502016);       // 26,214,400 B  [n][6400][64]
  u16* xA    = (u16*)(ws + 30716416);      // 26,214,400 B  [n][6400][64]
  u16* h     = (u16*)(ws + 56930816);      // 54,067,200 B  [n][6600][128]
  u16* wtb   = (u16*)(ws + 110998016);     // 294,912 B     [9][128][128]
  u16* wrb   = (u16*)(ws + 111292928);     // 16,384 B      [128][64]
  u16* w3b   = (u16*)(ws + 111309312);     // 16,384 B      [128][64]
  u16* w4b   = (u16*)(ws + 111325696);     // 16,384 B      [128][64]
  float* e0  = (float*)(ws + 111342080);   // 512 B
  float* e1  = (float*)(ws + 111342592);   // 512 B

  kaux<<<787, 256, 0, stream>>>(wt, wrw, g2, v2, gr, vr, w3, w4, bt, bb2, m2, bbr, mr, brb,
                                xm, wtb, wrb, w3b, w4b, e0, e1, h);
  kprep2<<<dim3(32,32), 512, 0, stream>>>(x, Ab, xT, xA);
  kmean<<<dim3(8,32), 256, 0, stream>>>(xT, xm);
  kp<<<dim3(32,32), 64, 0, stream>>>(xm, w2, b2p, Ab, p, rsA);
  ks<<<dim3(64,32), 256, 0, stream>>>(xT, w3b, p, s);
  ky<<<dim3(50,32), 256, 0, stream>>>(xA, w4b, s, b3, b4, g1, bb1, m1, v1, rsA, h);
  ktcn<<<dim3(50,32), 512, 0, stream>>>(h, wtb, wrb, xT, e0, e1, out);
}